// Round 1
// 2423.559 us; speedup vs baseline: 1.6518x; 1.6518x over previous
//
#include <hip/hip_runtime.h>
#include <hip/hip_bf16.h>

// ---------------------------------------------------------------------------
// RelInteraction pipeline, round 1: bf16x2-split MFMA GEMM for the 4 heavy
// GEMMs (steps 4, 6, 9, 10) + split-K for the occupancy-starved fc1/fc2.
// Layouts (all channel-minor for coalescing):
//   fm_t   [b][hw][c]      red   [b][hw][d]
//   filt_dw[n][c*9+ij]     filt_pw[n][d][c]
//   fd     [n][hw][c]      fp    [n][hw][d]
//   so     [p][hw][c2] (c2: 0..511 subj, 512..1023 obj)
//   x0     [p][d*49+hw]    x1,x2 [p][4096]
// ---------------------------------------------------------------------------

namespace {
constexpr int NIM  = 2;
constexpr int NOBJ = 64;
constexpr int NPAIR= 256;
constexpr int CCH  = 512;
constexpr int H = 28, W = 28, HW = 784;
constexpr int PP = 49;                 // 7x7 pool
constexpr int NREL = 51;
constexpr int PDIM = 4096;
constexpr int FLAT = CCH * PP;         // 25088

// workspace offsets in floats
constexpr long OFF_FMT = 0;                                   // 2*784*512
constexpr long OFF_RED = OFF_FMT + (long)NIM * HW * CCH;      // 2*784*512
constexpr long OFF_FDW = OFF_RED + (long)NIM * HW * CCH;      // 64*4608
constexpr long OFF_FPW = OFF_FDW + (long)NOBJ * CCH * 9;      // 64*512*512
constexpr long OFF_FD  = OFF_FPW + (long)NOBJ * CCH * CCH;    // 64*784*512
constexpr long OFF_FP  = OFF_FD  + (long)NOBJ * HW * CCH;     // 64*784*512
constexpr long OFF_X1  = OFF_FP  + (long)NOBJ * HW * CCH;     // 256*4096
constexpr long OFF_X2  = OFF_X1  + (long)NPAIR * PDIM;        // 256*4096
// reuse (lifetimes disjoint):
constexpr long OFF_SO  = OFF_FPW;   // 256*49*1024 = 12.8M <= 16.8M
constexpr long OFF_X0  = OFF_FD;    // 256*25088   =  6.4M <= 25.7M
constexpr long OFF_PART= OFF_FP;    // split-K partials: 16*1.05M = 16.8M <= 25.7M
} // namespace

typedef short bf16x8 __attribute__((ext_vector_type(8)));
typedef float f32x4  __attribute__((ext_vector_type(4)));

// --- transpose fmaps (b,c,p) -> fm_t (b,p,c) -------------------------------
__global__ void transpose_k(const float* __restrict__ in, float* __restrict__ out) {
    __shared__ float tile[32][33];
    const int b  = blockIdx.z;
    const int p0 = blockIdx.x * 32, c0 = blockIdx.y * 32;
    const int tx = threadIdx.x, ty = threadIdx.y;
    int p = p0 + tx, c = c0 + ty;
    if (p < HW && c < CCH) tile[ty][tx] = in[((long)b * CCH + c) * HW + p];
    __syncthreads();
    int p2 = p0 + ty, c2 = c0 + tx;
    if (p2 < HW && c2 < CCH) out[((long)b * HW + p2) * CCH + c2] = tile[tx][ty];
}

// --- generic NT GEMM (fp32 vector, kept for small/odd shapes) --------------
template<bool RELU, bool TROUT, bool HAS_BIAS>
__global__ __launch_bounds__(256)
void gemm_nt64(const float* __restrict__ A, const float* __restrict__ B,
               const float* __restrict__ bias, float* __restrict__ C,
               int M, int N, int K, long sA, long sB, long sC) {
    constexpr int BM = 64, BN = 64, BK = 16;
    __shared__ float As[BK][BM];
    __shared__ float Bs[BK][BN];
    A += (long)blockIdx.z * sA;
    B += (long)blockIdx.z * sB;
    C += (long)blockIdx.z * sC;
    const int m0 = blockIdx.x * BM;
    const int n0 = blockIdx.y * BN;
    const int tid  = threadIdx.x;
    const int lrow = tid >> 2;           // 0..63 (tile row for loads)
    const int lk4  = (tid & 3) << 2;     // 0,4,8,12
    const int tm   = (tid & 15) << 2;    // 0..60
    const int tn   = (tid >> 4) << 2;    // 0..60
    const int gma = m0 + lrow;
    const int gnb = n0 + lrow;
    const bool am = (gma < M);
    const bool bn = (gnb < N);
    const float* Ald = A + (long)gma * K + lk4;
    const float* Bld = B + (long)gnb * K + lk4;
    float acc[4][4] = {};
    for (int k0 = 0; k0 < K; k0 += BK) {
        float4 av = make_float4(0.f, 0.f, 0.f, 0.f);
        float4 bv = make_float4(0.f, 0.f, 0.f, 0.f);
        if (am) av = *(const float4*)(Ald + k0);
        if (bn) bv = *(const float4*)(Bld + k0);
        As[lk4 + 0][lrow] = av.x; As[lk4 + 1][lrow] = av.y;
        As[lk4 + 2][lrow] = av.z; As[lk4 + 3][lrow] = av.w;
        Bs[lk4 + 0][lrow] = bv.x; Bs[lk4 + 1][lrow] = bv.y;
        Bs[lk4 + 2][lrow] = bv.z; Bs[lk4 + 3][lrow] = bv.w;
        __syncthreads();
        #pragma unroll
        for (int kk = 0; kk < BK; ++kk) {
            float a[4], b[4];
            #pragma unroll
            for (int i = 0; i < 4; ++i) a[i] = As[kk][tm + i];
            #pragma unroll
            for (int j = 0; j < 4; ++j) b[j] = Bs[kk][tn + j];
            #pragma unroll
            for (int i = 0; i < 4; ++i)
                #pragma unroll
                for (int j = 0; j < 4; ++j)
                    acc[i][j] = fmaf(a[i], b[j], acc[i][j]);
        }
        __syncthreads();
    }
    #pragma unroll
    for (int i = 0; i < 4; ++i) {
        const int m = m0 + tm + i;
        if (m >= M) continue;
        #pragma unroll
        for (int j = 0; j < 4; ++j) {
            const int n = n0 + tn + j;
            if (n >= N) continue;
            float v = acc[i][j];
            if (HAS_BIAS) v += bias[n];
            if (RELU) v = fmaxf(v, 0.f);
            if (TROUT) C[(long)n * M + m] = v;
            else       C[(long)m * N + n] = v;
        }
    }
}

// --- bf16x2-split helper: fp32 -> (hi, lo) bf16 via truncation -------------
__device__ __forceinline__ void split_store(unsigned short* hp, unsigned short* lp,
                                            float4 v) {
    float f[4] = {v.x, v.y, v.z, v.w};
    ushort4 hv, lv;
    unsigned short h[4], l[4];
    #pragma unroll
    for (int t = 0; t < 4; ++t) {
        unsigned u = __float_as_uint(f[t]);
        h[t] = (unsigned short)(u >> 16);                       // hi = trunc-to-bf16
        float hf = __uint_as_float((unsigned)h[t] << 16);
        l[t] = (unsigned short)(__float_as_uint(f[t] - hf) >> 16); // lo = residual
    }
    hv.x = h[0]; hv.y = h[1]; hv.z = h[2]; hv.w = h[3];
    lv.x = l[0]; lv.y = l[1]; lv.z = l[2]; lv.w = l[3];
    *(ushort4*)hp = hv;
    *(ushort4*)lp = lv;
}

// --- NT GEMM via bf16x2-split MFMA (fp32-accurate) -------------------------
// C[m,n] = act(sum_k A[m,k]*B[n,k] + bias[n]).
// 128x128 tile, 4 waves (2x2), wave = 64x64 = 4x4 frags of 16x16x32 MFMA.
// Split-K / batch both via blockIdx.z + (sA,sB,sC) element strides;
// lda/ldb are full row strides (split-K keeps them at the full K).
// Kext must be a multiple of 32.
template<bool RELU, bool HAS_BIAS>
__global__ __launch_bounds__(256)
void gemm_nt_mfma(const float* __restrict__ A, const float* __restrict__ B,
                  const float* __restrict__ bias, float* __restrict__ C,
                  int M, int N, int Kext, int lda, int ldb,
                  long sA, long sB, long sC) {
    constexpr int BM = 128, BN = 128, BK = 32;
    constexpr int PAD = 40;   // padded k-stride (elements): 80B rows, 2-way banks
    __shared__ unsigned short Ah[BM][PAD], Al[BM][PAD];
    __shared__ unsigned short Bh[BN][PAD], Bl[BN][PAD];   // 4*10240B = 40KB LDS
    A += (long)blockIdx.z * sA;
    B += (long)blockIdx.z * sB;
    C += (long)blockIdx.z * sC;
    const int m0 = blockIdx.x * BM, n0 = blockIdx.y * BN;
    const int tid  = threadIdx.x;
    const int lane = tid & 63;
    const int wid  = tid >> 6;
    const int wm = (wid >> 1) * 64, wn = (wid & 1) * 64;  // wave origin in tile
    const int fr = lane & 15;           // frag row (A) / col (B,D)
    const int k8 = (lane >> 4) * 8;     // frag k-offset, 8 contiguous k per lane
    f32x4 zero4 = {0.f, 0.f, 0.f, 0.f};
    f32x4 acc[4][4];
    #pragma unroll
    for (int i = 0; i < 4; ++i)
        #pragma unroll
        for (int j = 0; j < 4; ++j) acc[i][j] = zero4;

    for (int k0 = 0; k0 < Kext; k0 += BK) {
        // stage 128x32 fp32 of A and B, split into hi/lo bf16 in LDS.
        // 256 thr * 4 iters * float4 = 1024 float4 = 128 rows x 8 float4.
        #pragma unroll
        for (int i = 0; i < 4; ++i) {
            const int idx = tid + i * 256;
            const int r = idx >> 3;
            const int c = (idx & 7) << 2;
            float4 av = make_float4(0.f, 0.f, 0.f, 0.f);
            float4 bv = make_float4(0.f, 0.f, 0.f, 0.f);
            if (m0 + r < M) av = *(const float4*)(A + (long)(m0 + r) * lda + k0 + c);
            if (n0 + r < N) bv = *(const float4*)(B + (long)(n0 + r) * ldb + k0 + c);
            split_store(&Ah[r][c], &Al[r][c], av);
            split_store(&Bh[r][c], &Bl[r][c], bv);
        }
        __syncthreads();
        bf16x8 ah[4], al[4], bh[4], bl[4];
        #pragma unroll
        for (int f = 0; f < 4; ++f) {
            ah[f] = *(const bf16x8*)&Ah[wm + f * 16 + fr][k8];
            al[f] = *(const bf16x8*)&Al[wm + f * 16 + fr][k8];
            bh[f] = *(const bf16x8*)&Bh[wn + f * 16 + fr][k8];
            bl[f] = *(const bf16x8*)&Bl[wn + f * 16 + fr][k8];
        }
        #pragma unroll
        for (int i = 0; i < 4; ++i)
            #pragma unroll
            for (int j = 0; j < 4; ++j) {
                acc[i][j] = __builtin_amdgcn_mfma_f32_16x16x32_bf16(ah[i], bh[j], acc[i][j], 0, 0, 0);
                acc[i][j] = __builtin_amdgcn_mfma_f32_16x16x32_bf16(ah[i], bl[j], acc[i][j], 0, 0, 0);
                acc[i][j] = __builtin_amdgcn_mfma_f32_16x16x32_bf16(al[i], bh[j], acc[i][j], 0, 0, 0);
            }
        __syncthreads();
    }
    // epilogue: D frag mapping col=lane&15, row=(lane>>4)*4+reg  [m89/m91]
    const int rg = (lane >> 4) << 2;
    #pragma unroll
    for (int i = 0; i < 4; ++i)
        #pragma unroll
        for (int j = 0; j < 4; ++j) {
            const int n = n0 + wn + j * 16 + fr;
            if (n >= N) continue;
            #pragma unroll
            for (int t = 0; t < 4; ++t) {
                const int m = m0 + wm + i * 16 + rg + t;
                if (m >= M) continue;
                float v = acc[i][j][t];
                if (HAS_BIAS) v += bias[n];
                if (RELU) v = fmaxf(v, 0.f);
                C[(long)m * N + n] = v;
            }
        }
}

// --- split-K reduction: out[i] = act(sum_s part[s][i] + bias[i & nmask]) ---
template<bool RELU>
__global__ __launch_bounds__(256)
void reduce_splitk(const float* __restrict__ part, const float* __restrict__ bias,
                   float* __restrict__ out, int MN, int nmask, int S) {
    const int i = blockIdx.x * 256 + threadIdx.x;
    if (i >= MN) return;
    float v = bias[i & nmask];
    for (int s = 0; s < S; ++s) v += part[(long)s * MN + i];
    out[i] = RELU ? fmaxf(v, 0.f) : v;
}

// --- depthwise 3x3 (same, zero-pad), per-object filters --------------------
__global__ void dwconv_k(const float* __restrict__ red, const float* __restrict__ fdw,
                         const float* __restrict__ rois, float* __restrict__ fd) {
    const int c  = threadIdx.x;      // 0..511
    const int hw = blockIdx.x;       // 0..783
    const int n  = blockIdx.y;       // 0..63
    const int y = hw / W, x = hw % W;
    const int b = (int)rois[n * 5];
    const float* rb = red + (long)b * HW * CCH;
    const float* w  = fdw + (long)n * (CCH * 9) + c * 9;
    float acc = 0.f;
    #pragma unroll
    for (int i = 0; i < 3; ++i) {
        const int yy = y + i - 1;
        if (yy < 0 || yy >= H) continue;
        #pragma unroll
        for (int j = 0; j < 3; ++j) {
            const int xx = x + j - 1;
            if (xx < 0 || xx >= W) continue;
            acc = fmaf(rb[(yy * W + xx) * CCH + c], w[i * 3 + j], acc);
        }
    }
    fd[((long)n * HW + hw) * CCH + c] = acc;
}

// --- ROI align (7x7, bilinear, matches reference exactly) ------------------
__global__ void roialign_k(const float* __restrict__ fp, const float* __restrict__ rois,
                           const int* __restrict__ rel, float* __restrict__ so) {
    const int c    = threadIdx.x;    // 0..511
    const int cell = blockIdx.x;     // 0..48
    const int side = blockIdx.y;     // 0 subj, 1 obj
    const int p    = blockIdx.z;     // 0..255
    const int o = rel[p * 3 + 1 + side];
    const float* box = rois + o * 5 + 1;
    const float b0 = box[0] / 16.f, b1 = box[1] / 16.f;
    const float b2 = box[2] / 16.f, b3 = box[3] / 16.f;
    const int py = cell / 7, px = cell % 7;
    const float gx = (px + 0.5f) / 7.f, gy = (py + 0.5f) / 7.f;
    float xs = b0 + gx * (b2 - b0);
    float ys = b1 + gy * (b3 - b1);
    xs = fminf(fmaxf(xs, 0.f), (float)(W - 1));
    ys = fminf(fmaxf(ys, 0.f), (float)(H - 1));
    const int x0 = (int)floorf(xs), y0 = (int)floorf(ys);
    const int x1 = min(x0 + 1, W - 1), y1 = min(y0 + 1, H - 1);
    const float wx = xs - (float)x0, wy = ys - (float)y0;
    const float* f = fp + (long)o * HW * CCH;
    const float f00 = f[(y0 * W + x0) * CCH + c];
    const float f01 = f[(y0 * W + x1) * CCH + c];
    const float f10 = f[(y1 * W + x0) * CCH + c];
    const float f11 = f[(y1 * W + x1) * CCH + c];
    const float v = f00 * (1.f - wy) * (1.f - wx) + f01 * (1.f - wy) * wx
                  + f10 * wy * (1.f - wx)         + f11 * wy * wx;
    so[((long)p * PP + cell) * (2 * CCH) + side * CCH + c] = v;
}

extern "C" void kernel_launch(void* const* d_in, const int* in_sizes, int n_in,
                              void* d_out, int out_size, void* d_ws, size_t ws_size,
                              hipStream_t stream) {
    const float* fmaps = (const float*)d_in[0];
    const float* rois  = (const float*)d_in[1];
    const int*   rel   = (const int*)  d_in[2];
    const float* feats = (const float*)d_in[3];
    const float* w_dw  = (const float*)d_in[4];
    const float* b_dw  = (const float*)d_in[5];
    const float* w_pw  = (const float*)d_in[6];
    const float* b_pw  = (const float*)d_in[7];
    const float* w_red = (const float*)d_in[8];
    const float* b_red = (const float*)d_in[9];
    const float* w_rec = (const float*)d_in[10];
    const float* b_rec = (const float*)d_in[11];
    const float* w_fc1 = (const float*)d_in[12];
    const float* b_fc1 = (const float*)d_in[13];
    const float* w_fc2 = (const float*)d_in[14];
    const float* b_fc2 = (const float*)d_in[15];
    const float* w_rel = (const float*)d_in[16];
    const float* b_rel = (const float*)d_in[17];

    float* ws  = (float*)d_ws;
    float* out = (float*)d_out;
    float* fmt = ws + OFF_FMT;
    float* red = ws + OFF_RED;
    float* fdw = ws + OFF_FDW;
    float* fpw = ws + OFF_FPW;
    float* fd  = ws + OFF_FD;
    float* fpb = ws + OFF_FP;
    float* so  = ws + OFF_SO;
    float* x0  = ws + OFF_X0;
    float* x1  = ws + OFF_X1;
    float* x2  = ws + OFF_X2;
    float* part= ws + OFF_PART;

    // 1. fmaps (b,c,hw) -> fm_t (b,hw,c)
    transpose_k<<<dim3(25, 16, 2), dim3(32, 32), 0, stream>>>(fmaps, fmt);

    // 2. red[b,hw,d] = relu(fm_t[b] @ w_red^T + b_red)   M=784 N=512 K=512, batch 2
    gemm_nt64<true, false, true><<<dim3(13, 8, 2), 256, 0, stream>>>(
        fmt, w_red, b_red, red, HW, CCH, CCH, (long)HW * CCH, 0, (long)HW * CCH);

    // 3. filt_dw = feats @ w_dw^T + b_dw                 M=64 N=4608 K=512
    gemm_nt64<false, false, true><<<dim3(1, 72, 1), 256, 0, stream>>>(
        feats, w_dw, b_dw, fdw, NOBJ, CCH * 9, CCH, 0, 0, 0);

    // 4. filt_pw = feats @ w_pw^T + b_pw   [MFMA]        M=64 N=262144 K=512
    gemm_nt_mfma<false, true><<<dim3(1, 2048, 1), 256, 0, stream>>>(
        feats, w_pw, b_pw, fpw, NOBJ, CCH * CCH, CCH, CCH, CCH, 0, 0, 0);

    // 5. depthwise 3x3: fd[n,hw,c]
    dwconv_k<<<dim3(HW, NOBJ), CCH, 0, stream>>>(red, fdw, rois, fd);

    // 6. fp[n,hw,d] = relu(fd[n] @ filt_pw[n]^T) [MFMA]  M=784 N=512 K=512, batch 64
    gemm_nt_mfma<true, false><<<dim3(7, 4, NOBJ), 256, 0, stream>>>(
        fd, fpw, nullptr, fpb, HW, CCH, CCH, CCH, CCH,
        (long)HW * CCH, (long)CCH * CCH, (long)HW * CCH);

    // 7. ROI align -> so[p,cell,c2]
    roialign_k<<<dim3(PP, 2, NPAIR), CCH, 0, stream>>>(fpb, rois, rel, so);

    // 8. rec: x0[p, d*49+hw] = so[p] @ w_rec^T + b_rec   M=49 N=512 K=1024, batch 256
    gemm_nt64<false, true, true><<<dim3(1, 8, NPAIR), 256, 0, stream>>>(
        so, w_rec, b_rec, x0, PP, CCH, 2 * CCH, (long)PP * 2 * CCH, 0, (long)FLAT);

    // 9. x1 = relu(x0 @ w_fc1^T + b_fc1)   [MFMA, split-K 16]  M=256 N=4096 K=25088
    {
        const int S = 16, Kc = FLAT / S;               // 1568, mult of 32
        gemm_nt_mfma<false, false><<<dim3(2, 32, S), 256, 0, stream>>>(
            x0, w_fc1, nullptr, part, NPAIR, PDIM, Kc, FLAT, FLAT,
            (long)Kc, (long)Kc, (long)NPAIR * PDIM);
        reduce_splitk<true><<<dim3((NPAIR * PDIM) / 256), 256, 0, stream>>>(
            part, b_fc1, x1, NPAIR * PDIM, PDIM - 1, S);
    }

    // 10. x2 = x1 @ w_fc2^T + b_fc2        [MFMA, split-K 4]   M=256 N=4096 K=4096
    {
        const int S = 4, Kc = PDIM / S;                // 1024, mult of 32
        gemm_nt_mfma<false, false><<<dim3(2, 32, S), 256, 0, stream>>>(
            x1, w_fc2, nullptr, part, NPAIR, PDIM, Kc, PDIM, PDIM,
            (long)Kc, (long)Kc, (long)NPAIR * PDIM);
        reduce_splitk<false><<<dim3((NPAIR * PDIM) / 256), 256, 0, stream>>>(
            part, b_fc2, x2, NPAIR * PDIM, PDIM - 1, S);
    }

    // 11. out = x2 @ w_rel^T + b_rel                     M=256 N=51 K=4096
    gemm_nt64<false, false, true><<<dim3(4, 1, 1), 256, 0, stream>>>(
        x2, w_rel, b_rel, out, NPAIR, NREL, PDIM, 0, 0, 0);
}

// Round 2
// 2357.178 us; speedup vs baseline: 1.6983x; 1.0282x over previous
//
#include <hip/hip_runtime.h>
#include <hip/hip_bf16.h>

// ---------------------------------------------------------------------------
// RelInteraction pipeline, round 2:
//  - MFMA GEMM gains T14 double-buffering (reg-stage next tile, raw s_barrier
//    + manual lgkmcnt so in-flight global loads are NOT drained at barriers).
//  - step 8 (rec) converted to one big MFMA GEMM (M=12544) with scatter-out.
//  - fc2 split-K widened to S=8.
// Layouts unchanged:
//   fm_t   [b][hw][c]      red   [b][hw][d]
//   filt_dw[n][c*9+ij]     filt_pw[n][d][c]
//   fd     [n][hw][c]      fp    [n][hw][d]
//   so     [p][hw][c2] (c2: 0..511 subj, 512..1023 obj)
//   x0     [p][d*49+hw]    x1,x2 [p][4096]
// ---------------------------------------------------------------------------

namespace {
constexpr int NIM  = 2;
constexpr int NOBJ = 64;
constexpr int NPAIR= 256;
constexpr int CCH  = 512;
constexpr int H = 28, W = 28, HW = 784;
constexpr int PP = 49;                 // 7x7 pool
constexpr int NREL = 51;
constexpr int PDIM = 4096;
constexpr int FLAT = CCH * PP;         // 25088

// workspace offsets in floats
constexpr long OFF_FMT = 0;                                   // 2*784*512
constexpr long OFF_RED = OFF_FMT + (long)NIM * HW * CCH;      // 2*784*512
constexpr long OFF_FDW = OFF_RED + (long)NIM * HW * CCH;      // 64*4608
constexpr long OFF_FPW = OFF_FDW + (long)NOBJ * CCH * 9;      // 64*512*512
constexpr long OFF_FD  = OFF_FPW + (long)NOBJ * CCH * CCH;    // 64*784*512
constexpr long OFF_FP  = OFF_FD  + (long)NOBJ * HW * CCH;     // 64*784*512
constexpr long OFF_X1  = OFF_FP  + (long)NOBJ * HW * CCH;     // 256*4096
constexpr long OFF_X2  = OFF_X1  + (long)NPAIR * PDIM;        // 256*4096
// reuse (lifetimes disjoint):
constexpr long OFF_SO  = OFF_FPW;   // 256*49*1024 = 12.8M <= 16.8M
constexpr long OFF_X0  = OFF_FD;    // 256*25088   =  6.4M <= 25.7M
constexpr long OFF_PART= OFF_FP;    // split-K partials: 16*1.05M = 16.8M <= 25.7M
} // namespace

typedef short bf16x8 __attribute__((ext_vector_type(8)));
typedef float f32x4  __attribute__((ext_vector_type(4)));

// --- transpose fmaps (b,c,p) -> fm_t (b,p,c) -------------------------------
__global__ void transpose_k(const float* __restrict__ in, float* __restrict__ out) {
    __shared__ float tile[32][33];
    const int b  = blockIdx.z;
    const int p0 = blockIdx.x * 32, c0 = blockIdx.y * 32;
    const int tx = threadIdx.x, ty = threadIdx.y;
    int p = p0 + tx, c = c0 + ty;
    if (p < HW && c < CCH) tile[ty][tx] = in[((long)b * CCH + c) * HW + p];
    __syncthreads();
    int p2 = p0 + ty, c2 = c0 + tx;
    if (p2 < HW && c2 < CCH) out[((long)b * HW + p2) * CCH + c2] = tile[tx][ty];
}

// --- generic NT GEMM (fp32 vector, for small/odd shapes: steps 2,3,11) -----
template<bool RELU, bool TROUT, bool HAS_BIAS>
__global__ __launch_bounds__(256)
void gemm_nt64(const float* __restrict__ A, const float* __restrict__ B,
               const float* __restrict__ bias, float* __restrict__ C,
               int M, int N, int K, long sA, long sB, long sC) {
    constexpr int BM = 64, BN = 64, BK = 16;
    __shared__ float As[BK][BM];
    __shared__ float Bs[BK][BN];
    A += (long)blockIdx.z * sA;
    B += (long)blockIdx.z * sB;
    C += (long)blockIdx.z * sC;
    const int m0 = blockIdx.x * BM;
    const int n0 = blockIdx.y * BN;
    const int tid  = threadIdx.x;
    const int lrow = tid >> 2;           // 0..63 (tile row for loads)
    const int lk4  = (tid & 3) << 2;     // 0,4,8,12
    const int tm   = (tid & 15) << 2;    // 0..60
    const int tn   = (tid >> 4) << 2;    // 0..60
    const int gma = m0 + lrow;
    const int gnb = n0 + lrow;
    const bool am = (gma < M);
    const bool bn = (gnb < N);
    const float* Ald = A + (long)gma * K + lk4;
    const float* Bld = B + (long)gnb * K + lk4;
    float acc[4][4] = {};
    for (int k0 = 0; k0 < K; k0 += BK) {
        float4 av = make_float4(0.f, 0.f, 0.f, 0.f);
        float4 bv = make_float4(0.f, 0.f, 0.f, 0.f);
        if (am) av = *(const float4*)(Ald + k0);
        if (bn) bv = *(const float4*)(Bld + k0);
        As[lk4 + 0][lrow] = av.x; As[lk4 + 1][lrow] = av.y;
        As[lk4 + 2][lrow] = av.z; As[lk4 + 3][lrow] = av.w;
        Bs[lk4 + 0][lrow] = bv.x; Bs[lk4 + 1][lrow] = bv.y;
        Bs[lk4 + 2][lrow] = bv.z; Bs[lk4 + 3][lrow] = bv.w;
        __syncthreads();
        #pragma unroll
        for (int kk = 0; kk < BK; ++kk) {
            float a[4], b[4];
            #pragma unroll
            for (int i = 0; i < 4; ++i) a[i] = As[kk][tm + i];
            #pragma unroll
            for (int j = 0; j < 4; ++j) b[j] = Bs[kk][tn + j];
            #pragma unroll
            for (int i = 0; i < 4; ++i)
                #pragma unroll
                for (int j = 0; j < 4; ++j)
                    acc[i][j] = fmaf(a[i], b[j], acc[i][j]);
        }
        __syncthreads();
    }
    #pragma unroll
    for (int i = 0; i < 4; ++i) {
        const int m = m0 + tm + i;
        if (m >= M) continue;
        #pragma unroll
        for (int j = 0; j < 4; ++j) {
            const int n = n0 + tn + j;
            if (n >= N) continue;
            float v = acc[i][j];
            if (HAS_BIAS) v += bias[n];
            if (RELU) v = fmaxf(v, 0.f);
            if (TROUT) C[(long)n * M + m] = v;
            else       C[(long)m * N + n] = v;
        }
    }
}

// --- bf16x2-split helper: fp32 -> (hi, lo) bf16 via truncation -------------
__device__ __forceinline__ void split_store(unsigned short* hp, unsigned short* lp,
                                            float4 v) {
    float f[4] = {v.x, v.y, v.z, v.w};
    ushort4 hv, lv;
    unsigned short h[4], l[4];
    #pragma unroll
    for (int t = 0; t < 4; ++t) {
        unsigned u = __float_as_uint(f[t]);
        h[t] = (unsigned short)(u >> 16);                       // hi = trunc-to-bf16
        float hf = __uint_as_float((unsigned)h[t] << 16);
        l[t] = (unsigned short)(__float_as_uint(f[t] - hf) >> 16); // lo = residual
    }
    hv.x = h[0]; hv.y = h[1]; hv.z = h[2]; hv.w = h[3];
    lv.x = l[0]; lv.y = l[1]; lv.z = l[2]; lv.w = l[3];
    *(ushort4*)hp = hv;
    *(ushort4*)lp = lv;
}

// --- NT GEMM via bf16x2-split MFMA (fp32-accurate), double-buffered --------
// C[m,n] = act(sum_k A[m,k]*B[n,k] + bias[n]).
// 128x128 tile, 4 waves (2x2), wave = 64x64 = 4x4 frags of 16x16x32 MFMA.
// Pipeline per K-iter: ds_write tile t (from regs) -> issue global loads t+1
// -> lgkmcnt(0) + raw s_barrier (loads stay in flight, no vmcnt drain)
// -> ds_read + MFMA -> raw s_barrier. OUTMODE: 0 = C[m*N+n],
// 1 = rec-scatter C[(m/49)*FLAT + n*49 + m%49].
template<bool RELU, bool HAS_BIAS, int OUTMODE>
__global__ __launch_bounds__(256, 3)
void gemm_nt_mfma(const float* __restrict__ A, const float* __restrict__ B,
                  const float* __restrict__ bias, float* __restrict__ C,
                  int M, int N, int Kext, int lda, int ldb,
                  long sA, long sB, long sC) {
    constexpr int BM = 128, BN = 128, BK = 32;
    constexpr int PAD = 40;   // padded k-stride (elements): 80B rows
    __shared__ unsigned short Ah[BM][PAD], Al[BM][PAD];
    __shared__ unsigned short Bh[BN][PAD], Bl[BN][PAD];   // 40KB LDS
    A += (long)blockIdx.z * sA;
    B += (long)blockIdx.z * sB;
    C += (long)blockIdx.z * sC;
    const int m0 = blockIdx.x * BM, n0 = blockIdx.y * BN;
    const int tid  = threadIdx.x;
    const int lane = tid & 63;
    const int wid  = tid >> 6;
    const int wm = (wid >> 1) * 64, wn = (wid & 1) * 64;  // wave origin in tile
    const int fr = lane & 15;           // frag row (A) / col (B,D)
    const int k8 = (lane >> 4) * 8;     // frag k-offset, 8 contiguous k per lane
    const int r0 = tid >> 3;            // staging row base (0..31)
    const int cc = (tid & 7) << 2;      // staging k-offset (0,4,..,28)
    const float4 f4z = make_float4(0.f, 0.f, 0.f, 0.f);
    f32x4 acc[4][4];
    #pragma unroll
    for (int i = 0; i < 4; ++i)
        #pragma unroll
        for (int j = 0; j < 4; ++j) acc[i][j] = f32x4{0.f, 0.f, 0.f, 0.f};

    float4 nA[4], nB[4];
    auto issue = [&](int k0) {
        #pragma unroll
        for (int i = 0; i < 4; ++i) {
            const int r = r0 + i * 32;
            nA[i] = (m0 + r < M) ? *(const float4*)(A + (long)(m0 + r) * lda + k0 + cc) : f4z;
            nB[i] = (n0 + r < N) ? *(const float4*)(B + (long)(n0 + r) * ldb + k0 + cc) : f4z;
        }
    };
    issue(0);
    const int niter = Kext / BK;
    for (int t = 0; t < niter; ++t) {
        // write tile t from regs into LDS (split into hi/lo bf16)
        #pragma unroll
        for (int i = 0; i < 4; ++i) {
            const int r = r0 + i * 32;
            split_store(&Ah[r][cc], &Al[r][cc], nA[i]);
            split_store(&Bh[r][cc], &Bl[r][cc], nB[i]);
        }
        // issue next tile's global loads; they stay in flight across MFMA
        if (t + 1 < niter) issue((t + 1) * BK);
        asm volatile("s_waitcnt lgkmcnt(0)" ::: "memory");  // ds_writes visible
        __builtin_amdgcn_s_barrier();                        // no vmcnt drain
        bf16x8 ah[4], al[4], bh[4], bl[4];
        #pragma unroll
        for (int f = 0; f < 4; ++f) {
            ah[f] = *(const bf16x8*)&Ah[wm + f * 16 + fr][k8];
            al[f] = *(const bf16x8*)&Al[wm + f * 16 + fr][k8];
            bh[f] = *(const bf16x8*)&Bh[wn + f * 16 + fr][k8];
            bl[f] = *(const bf16x8*)&Bl[wn + f * 16 + fr][k8];
        }
        #pragma unroll
        for (int i = 0; i < 4; ++i)
            #pragma unroll
            for (int j = 0; j < 4; ++j) {
                acc[i][j] = __builtin_amdgcn_mfma_f32_16x16x32_bf16(ah[i], bh[j], acc[i][j], 0, 0, 0);
                acc[i][j] = __builtin_amdgcn_mfma_f32_16x16x32_bf16(ah[i], bl[j], acc[i][j], 0, 0, 0);
                acc[i][j] = __builtin_amdgcn_mfma_f32_16x16x32_bf16(al[i], bh[j], acc[i][j], 0, 0, 0);
            }
        __builtin_amdgcn_s_barrier();   // LDS reads done before next writes
    }
    // epilogue: D frag mapping col=lane&15, row=(lane>>4)*4+reg  [m89/m91]
    const int rg = (lane >> 4) << 2;
    #pragma unroll
    for (int i = 0; i < 4; ++i)
        #pragma unroll
        for (int j = 0; j < 4; ++j) {
            const int n = n0 + wn + j * 16 + fr;
            if (n >= N) continue;
            #pragma unroll
            for (int t = 0; t < 4; ++t) {
                const int m = m0 + wm + i * 16 + rg + t;
                if (m >= M) continue;
                float v = acc[i][j][t];
                if (HAS_BIAS) v += bias[n];
                if (RELU) v = fmaxf(v, 0.f);
                if (OUTMODE == 0) {
                    C[(long)m * N + n] = v;
                } else {  // rec scatter: m = p*49+hw -> x0[p][n*49+hw]
                    const int p = m / PP, hw = m - p * PP;
                    C[(long)p * FLAT + (long)n * PP + hw] = v;
                }
            }
        }
}

// --- split-K reduction: out[i] = act(sum_s part[s][i] + bias[i & nmask]) ---
template<bool RELU>
__global__ __launch_bounds__(256)
void reduce_splitk(const float* __restrict__ part, const float* __restrict__ bias,
                   float* __restrict__ out, int MN, int nmask, int S) {
    const int i = blockIdx.x * 256 + threadIdx.x;
    if (i >= MN) return;
    float v = bias[i & nmask];
    for (int s = 0; s < S; ++s) v += part[(long)s * MN + i];
    out[i] = RELU ? fmaxf(v, 0.f) : v;
}

// --- depthwise 3x3 (same, zero-pad), per-object filters --------------------
__global__ void dwconv_k(const float* __restrict__ red, const float* __restrict__ fdw,
                         const float* __restrict__ rois, float* __restrict__ fd) {
    const int c  = threadIdx.x;      // 0..511
    const int hw = blockIdx.x;       // 0..783
    const int n  = blockIdx.y;       // 0..63
    const int y = hw / W, x = hw % W;
    const int b = (int)rois[n * 5];
    const float* rb = red + (long)b * HW * CCH;
    const float* w  = fdw + (long)n * (CCH * 9) + c * 9;
    float acc = 0.f;
    #pragma unroll
    for (int i = 0; i < 3; ++i) {
        const int yy = y + i - 1;
        if (yy < 0 || yy >= H) continue;
        #pragma unroll
        for (int j = 0; j < 3; ++j) {
            const int xx = x + j - 1;
            if (xx < 0 || xx >= W) continue;
            acc = fmaf(rb[(yy * W + xx) * CCH + c], w[i * 3 + j], acc);
        }
    }
    fd[((long)n * HW + hw) * CCH + c] = acc;
}

// --- ROI align (7x7, bilinear, matches reference exactly) ------------------
__global__ void roialign_k(const float* __restrict__ fp, const float* __restrict__ rois,
                           const int* __restrict__ rel, float* __restrict__ so) {
    const int c    = threadIdx.x;    // 0..511
    const int cell = blockIdx.x;     // 0..48
    const int side = blockIdx.y;     // 0 subj, 1 obj
    const int p    = blockIdx.z;     // 0..255
    const int o = rel[p * 3 + 1 + side];
    const float* box = rois + o * 5 + 1;
    const float b0 = box[0] / 16.f, b1 = box[1] / 16.f;
    const float b2 = box[2] / 16.f, b3 = box[3] / 16.f;
    const int py = cell / 7, px = cell % 7;
    const float gx = (px + 0.5f) / 7.f, gy = (py + 0.5f) / 7.f;
    float xs = b0 + gx * (b2 - b0);
    float ys = b1 + gy * (b3 - b1);
    xs = fminf(fmaxf(xs, 0.f), (float)(W - 1));
    ys = fminf(fmaxf(ys, 0.f), (float)(H - 1));
    const int x0 = (int)floorf(xs), y0 = (int)floorf(ys);
    const int x1 = min(x0 + 1, W - 1), y1 = min(y0 + 1, H - 1);
    const float wx = xs - (float)x0, wy = ys - (float)y0;
    const float* f = fp + (long)o * HW * CCH;
    const float f00 = f[(y0 * W + x0) * CCH + c];
    const float f01 = f[(y0 * W + x1) * CCH + c];
    const float f10 = f[(y1 * W + x0) * CCH + c];
    const float f11 = f[(y1 * W + x1) * CCH + c];
    const float v = f00 * (1.f - wy) * (1.f - wx) + f01 * (1.f - wy) * wx
                  + f10 * wy * (1.f - wx)         + f11 * wy * wx;
    so[((long)p * PP + cell) * (2 * CCH) + side * CCH + c] = v;
}

extern "C" void kernel_launch(void* const* d_in, const int* in_sizes, int n_in,
                              void* d_out, int out_size, void* d_ws, size_t ws_size,
                              hipStream_t stream) {
    const float* fmaps = (const float*)d_in[0];
    const float* rois  = (const float*)d_in[1];
    const int*   rel   = (const int*)  d_in[2];
    const float* feats = (const float*)d_in[3];
    const float* w_dw  = (const float*)d_in[4];
    const float* b_dw  = (const float*)d_in[5];
    const float* w_pw  = (const float*)d_in[6];
    const float* b_pw  = (const float*)d_in[7];
    const float* w_red = (const float*)d_in[8];
    const float* b_red = (const float*)d_in[9];
    const float* w_rec = (const float*)d_in[10];
    const float* b_rec = (const float*)d_in[11];
    const float* w_fc1 = (const float*)d_in[12];
    const float* b_fc1 = (const float*)d_in[13];
    const float* w_fc2 = (const float*)d_in[14];
    const float* b_fc2 = (const float*)d_in[15];
    const float* w_rel = (const float*)d_in[16];
    const float* b_rel = (const float*)d_in[17];

    float* ws  = (float*)d_ws;
    float* out = (float*)d_out;
    float* fmt = ws + OFF_FMT;
    float* red = ws + OFF_RED;
    float* fdw = ws + OFF_FDW;
    float* fpw = ws + OFF_FPW;
    float* fd  = ws + OFF_FD;
    float* fpb = ws + OFF_FP;
    float* so  = ws + OFF_SO;
    float* x0  = ws + OFF_X0;
    float* x1  = ws + OFF_X1;
    float* x2  = ws + OFF_X2;
    float* part= ws + OFF_PART;

    // 1. fmaps (b,c,hw) -> fm_t (b,hw,c)
    transpose_k<<<dim3(25, 16, 2), dim3(32, 32), 0, stream>>>(fmaps, fmt);

    // 2. red[b,hw,d] = relu(fm_t[b] @ w_red^T + b_red)   M=784 N=512 K=512, batch 2
    gemm_nt64<true, false, true><<<dim3(13, 8, 2), 256, 0, stream>>>(
        fmt, w_red, b_red, red, HW, CCH, CCH, (long)HW * CCH, 0, (long)HW * CCH);

    // 3. filt_dw = feats @ w_dw^T + b_dw                 M=64 N=4608 K=512
    gemm_nt64<false, false, true><<<dim3(1, 72, 1), 256, 0, stream>>>(
        feats, w_dw, b_dw, fdw, NOBJ, CCH * 9, CCH, 0, 0, 0);

    // 4. filt_pw = feats @ w_pw^T + b_pw   [MFMA]        M=64 N=262144 K=512
    gemm_nt_mfma<false, true, 0><<<dim3(1, 2048, 1), 256, 0, stream>>>(
        feats, w_pw, b_pw, fpw, NOBJ, CCH * CCH, CCH, CCH, CCH, 0, 0, 0);

    // 5. depthwise 3x3: fd[n,hw,c]
    dwconv_k<<<dim3(HW, NOBJ), CCH, 0, stream>>>(red, fdw, rois, fd);

    // 6. fp[n,hw,d] = relu(fd[n] @ filt_pw[n]^T) [MFMA]  M=784 N=512 K=512, batch 64
    gemm_nt_mfma<true, false, 0><<<dim3(7, 4, NOBJ), 256, 0, stream>>>(
        fd, fpw, nullptr, fpb, HW, CCH, CCH, CCH, CCH,
        (long)HW * CCH, (long)CCH * CCH, (long)HW * CCH);

    // 7. ROI align -> so[p,cell,c2]
    roialign_k<<<dim3(PP, 2, NPAIR), CCH, 0, stream>>>(fpb, rois, rel, so);

    // 8. rec as ONE GEMM: M=256*49=12544, N=512, K=1024  [MFMA, scatter-out]
    //    x0[p][n*49+hw] = so[p*49+hw] @ w_rec^T + b_rec
    gemm_nt_mfma<false, true, 1><<<dim3(98, 4, 1), 256, 0, stream>>>(
        so, w_rec, b_rec, x0, NPAIR * PP, CCH, 2 * CCH, 2 * CCH, 2 * CCH, 0, 0, 0);

    // 9. x1 = relu(x0 @ w_fc1^T + b_fc1)   [MFMA, split-K 16]  M=256 N=4096 K=25088
    {
        const int S = 16, Kc = FLAT / S;               // 1568, mult of 32
        gemm_nt_mfma<false, false, 0><<<dim3(2, 32, S), 256, 0, stream>>>(
            x0, w_fc1, nullptr, part, NPAIR, PDIM, Kc, FLAT, FLAT,
            (long)Kc, (long)Kc, (long)NPAIR * PDIM);
        reduce_splitk<true><<<dim3((NPAIR * PDIM) / 256), 256, 0, stream>>>(
            part, b_fc1, x1, NPAIR * PDIM, PDIM - 1, S);
    }

    // 10. x2 = x1 @ w_fc2^T + b_fc2        [MFMA, split-K 8]   M=256 N=4096 K=4096
    {
        const int S = 8, Kc = PDIM / S;                // 512, mult of 32
        gemm_nt_mfma<false, false, 0><<<dim3(2, 32, S), 256, 0, stream>>>(
            x1, w_fc2, nullptr, part, NPAIR, PDIM, Kc, PDIM, PDIM,
            (long)Kc, (long)Kc, (long)NPAIR * PDIM);
        reduce_splitk<false><<<dim3((NPAIR * PDIM) / 256), 256, 0, stream>>>(
            part, b_fc2, x2, NPAIR * PDIM, PDIM - 1, S);
    }

    // 11. out = x2 @ w_rel^T + b_rel                     M=256 N=51 K=4096
    gemm_nt64<false, false, true><<<dim3(4, 1, 1), 256, 0, stream>>>(
        x2, w_rel, b_rel, out, NPAIR, NREL, PDIM, 0, 0, 0);
}